// Round 14
// baseline (176.303 us; speedup 1.0000x reference)
//
#include <hip/hip_runtime.h>

#define NF 256
#define H_ 8
#define M_ 32768

typedef _Float16 f16;
typedef _Float16 f16x8 __attribute__((ext_vector_type(8)));
typedef float f32x4 __attribute__((ext_vector_type(4)));
typedef unsigned short u16x8 __attribute__((ext_vector_type(8)));
typedef unsigned int u32x2 __attribute__((ext_vector_type(2)));
typedef unsigned int u32x4 __attribute__((ext_vector_type(4)));

#define GLOAD16(src, dst) \
  __builtin_amdgcn_global_load_lds((const __attribute__((address_space(1))) void*)(src), \
                                   (__attribute__((address_space(3))) void*)(dst), 16, 0, 0)

#define LDS_FENCE() do { asm volatile("s_waitcnt lgkmcnt(0)" ::: "memory"); \
                         __builtin_amdgcn_sched_barrier(0); } while (0)
#define SBAR() asm volatile("s_barrier" ::: "memory")

// ---------------- 256^2 8-phase GEMM core, BK=32 (64 KB LDS -> 2 blocks/CU) ----------------
// Per K-tile (K=32): 4 phases x {2 A-frag ds_reads | 1 half-tile stage -> bar ->
// lgkm0 -> 8 MFMA -> bar}. B(t+2) staged into CURRENT B slot (B(t) hoisted to regs
// at phase 1; phase-2 barrier guarantees all waves past their phase-1 lgkm0).
// Boundary vmcnt(2): by issue order (A1,A2,B1,B2 per tile) everything except
// B(t+2)'s 2 loads has landed -> A(t+1),B(t+1) guaranteed. Tail t=14: vmcnt(0).
// Swizzle: 16B slot p of row r holds global slot p ^ ((r^(r>>2))&3) — frag reads
// land 2 lanes/bank (free, m136).

__device__ __forceinline__ void stageHT32(const f16* __restrict__ g, int r0, int k0,
                                          f16* ldst, int tt) {
    const int r = tt >> 2;                       // 0..127
    const int p = tt & 3;
    const int key = (r ^ (r >> 2)) & 3;
    // LDS dest is linear in lane (wave*1024B + lane*16B) — gload_lds constraint.
    GLOAD16(g + (size_t)(r0 + r) * 512 + k0 + ((p ^ key) << 3), ldst + r * 32 + p * 8);
}

__device__ __forceinline__ void gemm256_core(const f16* __restrict__ A, const f16* __restrict__ W,
                                             int m0, int n0, f16* lds,
                                             f32x4 (&acc)[8][4], int wave, int lane) {
    const int wr = wave & 1, wc = wave >> 1;
    const int l15 = lane & 15, l4 = lane >> 4;
    const int tt = wave * 64 + lane;
    // buf(t) = lds + (t&1)*16384 : A[256][32] at +0, B[256][32] at +8192 (f16 idx)
    stageHT32(W, n0,        0, lds + 8192,          tt);   // B1(0)
    stageHT32(W, n0 + 128,  0, lds + 8192 + 4096,   tt);   // B2(0)
    stageHT32(A, m0,        0, lds,                 tt);   // A1(0)
    stageHT32(A, m0 + 128,  0, lds + 4096,          tt);   // A2(0)
    stageHT32(W, n0,       32, lds + 16384 + 8192,  tt);   // B1(1)
    stageHT32(W, n0 + 128, 32, lds + 16384 + 12288, tt);   // B2(1)
    asm volatile("s_waitcnt vmcnt(2)" ::: "memory");       // B(0),A(0) landed; B(1) in flight
    SBAR();
#pragma unroll
    for (int t = 0; t < 16; ++t) {
        f16* bufA = lds + (t & 1) * 16384;
        f16* bufB = bufA + 8192;
        f16* nA   = lds + ((t & 1) ^ 1) * 16384;
        f16x8 bfr[4];
#pragma unroll
        for (int j = 0; j < 4; ++j) {
            int rb = wc * 64 + j * 16 + l15;
            bfr[j] = *reinterpret_cast<const f16x8*>(
                bufB + rb * 32 + ((l4 ^ ((rb ^ (rb >> 2)) & 3)) << 3));
        }
#pragma unroll
        for (int q = 0; q < 4; ++q) {
            f16x8 afr[2];
#pragma unroll
            for (int rf = 0; rf < 2; ++rf) {
                int ra = wr * 128 + q * 32 + rf * 16 + l15;
                afr[rf] = *reinterpret_cast<const f16x8*>(
                    bufA + ra * 32 + ((l4 ^ ((ra ^ (ra >> 2)) & 3)) << 3));
            }
            if (q == 0 && t < 15) stageHT32(A, m0,       (t + 1) * 32, nA,          tt);
            if (q == 1 && t < 15) stageHT32(A, m0 + 128, (t + 1) * 32, nA + 4096,   tt);
            if (q == 2 && t < 14) stageHT32(W, n0,       (t + 2) * 32, bufB,        tt);
            if (q == 3 && t < 14) stageHT32(W, n0 + 128, (t + 2) * 32, bufB + 4096, tt);
            SBAR();
            LDS_FENCE();
            __builtin_amdgcn_s_setprio(1);
#pragma unroll
            for (int rf = 0; rf < 2; ++rf)
#pragma unroll
                for (int j = 0; j < 4; ++j)
                    acc[q * 2 + rf][j] = __builtin_amdgcn_mfma_f32_16x16x32_f16(
                        afr[rf], bfr[j], acc[q * 2 + rf][j], 0, 0, 0);
            __builtin_amdgcn_s_setprio(0);
            if (q < 3) SBAR();
        }
        if (t < 14) { asm volatile("s_waitcnt vmcnt(2)" ::: "memory"); }
        else        { asm volatile("s_waitcnt vmcnt(0)" ::: "memory"); }
        SBAR();
    }
}

// ---------------- conversion / prep ----------------

#define QSCALE 0.1803368801111204f   // (1/8) * log2(e)

__global__ void prep_all(const float* __restrict__ x, f16* __restrict__ xh,
                         const float* __restrict__ Wq, const float* __restrict__ Wk,
                         const float* __restrict__ Wv, const float* __restrict__ Wo,
                         const float* __restrict__ bq, const float* __restrict__ bk,
                         const float* __restrict__ bv, const int* __restrict__ adj,
                         f16* __restrict__ Wh, f16* __restrict__ Woh,
                         float* __restrict__ biasAll, unsigned long long* __restrict__ bmask) {
    if (blockIdx.x < 2048) {
        int idx = blockIdx.x * 256 + threadIdx.x;
        for (; idx < M_ * 512 / 8; idx += 2048 * 256) {
            const float4* s = reinterpret_cast<const float4*>(x + (size_t)idx * 8);
            float4 v0 = s[0], v1 = s[1];
            f16x8 o;
            o[0] = (f16)v0.x; o[1] = (f16)v0.y; o[2] = (f16)v0.z; o[3] = (f16)v0.w;
            o[4] = (f16)v1.x; o[5] = (f16)v1.y; o[6] = (f16)v1.z; o[7] = (f16)v1.w;
            *reinterpret_cast<f16x8*>(xh + (size_t)idx * 8) = o;
        }
        return;
    }
    const int tid = (blockIdx.x - 2048) * 256 + threadIdx.x;
    {
        const float* s; f16* d; float sc = 1.0f;
        int pp = tid >> 15, off = tid & 32767;
        if (pp == 0)      { s = Wq; d = Wh;              sc = QSCALE; }
        else if (pp == 1) { s = Wk; d = Wh + 512 * 512; }
        else if (pp == 2) { s = Wv; d = Wh + 2 * 512 * 512; }
        else              { s = Wo; d = Woh; }
        const float4* sv4 = reinterpret_cast<const float4*>(s + (size_t)off * 8);
        float4 v0 = sv4[0], v1 = sv4[1];
        f16x8 o;
        o[0] = (f16)(v0.x * sc); o[1] = (f16)(v0.y * sc);
        o[2] = (f16)(v0.z * sc); o[3] = (f16)(v0.w * sc);
        o[4] = (f16)(v1.x * sc); o[5] = (f16)(v1.y * sc);
        o[6] = (f16)(v1.z * sc); o[7] = (f16)(v1.w * sc);
        *reinterpret_cast<f16x8*>(d + (size_t)off * 8) = o;
    }
    if (tid < 1536) {
        float v = (tid < 512) ? QSCALE * bq[tid] : (tid < 1024) ? bk[tid - 512] : bv[tid - 1024];
        biasAll[tid] = v;
    }
    if (tid < 65536) {
        unsigned long long bal = __ballot(adj[tid] > 0);
        if ((tid & 63) == 0) bmask[tid >> 6] = bal;
    }
}

// ---------------- fused QKV GEMM ----------------
// q,k tiles (n0<1024) -> qkvb [M][1024] via 4x 64-row [64][264] epi passes.
// v tiles (n0>=1024) -> vT via 4x 64-nf transposed [256][72] epi passes.

__global__ __launch_bounds__(512) void qkv_gemm(const f16* __restrict__ A, const f16* __restrict__ W,
                                                const float* __restrict__ biasAll,
                                                f16* __restrict__ out, f16* __restrict__ vT) {
    __shared__ __align__(16) f16 lds[32768];     // 64 KB -> 2 blocks/CU
    const int tt = threadIdx.x, wave = tt >> 6, lane = tt & 63;
    const int lb = blockIdx.x, xcd = lb & 7, idx = lb >> 3;
    const int m0 = (xcd * 16 + idx / 6) * 256;
    const int n0 = (idx % 6) * 256;
    f32x4 acc[8][4] = {};
    gemm256_core(A, W, m0, n0, lds, acc, wave, lane);

    const int wr = wave & 1, wc = wave >> 1;
    const int l15 = lane & 15, l4 = lane >> 4;
    f16* epi = lds;
    const bool isV = (n0 >= 1024);
    float bb[4];
#pragma unroll
    for (int bc = 0; bc < 4; ++bc) bb[bc] = biasAll[n0 + wc * 64 + bc * 16 + l15];
#pragma unroll
    for (int c = 0; c < 4; ++c) {    // 64 output-rows (q/k) or 64 nf (v) per pass
        if (wr == (c >> 1)) {
            if (!isV) {
#pragma unroll
                for (int a2 = 0; a2 < 4; ++a2) {
                    int ar = (c & 1) * 4 + a2;
#pragma unroll
                    for (int bc = 0; bc < 4; ++bc)
#pragma unroll
                        for (int r = 0; r < 4; ++r)
                            epi[(a2 * 16 + l4 * 4 + r) * 264 + wc * 64 + bc * 16 + l15] =
                                (f16)(acc[ar][bc][r] + bb[bc]);
                }
            } else {
                // transposed: epiT[dk_local][nf_local], stride 72 (144 B, 16B-aligned rows)
#pragma unroll
                for (int a2 = 0; a2 < 4; ++a2) {
                    int ar = (c & 1) * 4 + a2;
#pragma unroll
                    for (int bc = 0; bc < 4; ++bc)
#pragma unroll
                        for (int r = 0; r < 4; ++r)
                            epi[(wc * 64 + bc * 16 + l15) * 72 + a2 * 16 + l4 * 4 + r] =
                                (f16)(acc[ar][bc][r] + bb[bc]);
                }
            }
        }
        LDS_FENCE();
        SBAR();
        if (!isV) {
#pragma unroll
            for (int p = 0; p < 4; ++p) {
                int row = p * 16 + (tt >> 5);
                *reinterpret_cast<f16x8*>(
                    out + (size_t)(m0 + c * 64 + row) * 1024 + n0 + (tt & 31) * 8) =
                    *reinterpret_cast<const f16x8*>(epi + row * 264 + (tt & 31) * 8);
            }
        } else {
            f16* vdst = vT + (size_t)(m0 >> 8) * 8 * 64 * 256 + (size_t)(n0 - 1024) * 256;
            const int dk = tt >> 1;
#pragma unroll
            for (int i = 0; i < 4; ++i) {
                int nfl = (tt & 1) * 32 + i * 8;
                *reinterpret_cast<f16x8*>(vdst + (size_t)dk * 256 + c * 64 + nfl) =
                    *reinterpret_cast<const f16x8*>(epi + dk * 72 + nfl);
            }
        }
        SBAR();
    }
}

// ---------------- attention (swapped QK^T, fused per-kkp drain+PV — unchanged R12) ----------------

template <int NR>
__device__ __forceinline__ void stage_rows512(const f16* __restrict__ g, int ld, int coff,
                                              f16* ldsb, int wave, int lane) {
    const int rr = wave * 8 + (lane >> 3);
    const int p  = lane & 7;
#pragma unroll
    for (int i = 0; i < NR / 64; ++i) {
        int r = i * 64 + rr;
        int col = ((p ^ (r & 7)) << 3);
        GLOAD16(g + (size_t)r * ld + coff + col, ldsb + (i * 64 + wave * 8) * 64);
    }
}

// V^T panel [64 dk][256 nf] viewed as 256 rows (rv = dk*4+chunk) of 64 f16,
// swizzle key = (rv ^ (rv>>3)) & 7 on the 16B slot.
__device__ __forceinline__ void stage_v512(const f16* __restrict__ g, f16* ldsb,
                                           int wave, int lane) {
    const int rr = wave * 8 + (lane >> 3);
    const int p  = lane & 7;
#pragma unroll
    for (int i = 0; i < 4; ++i) {
        int r = i * 64 + rr;
        int key = (r ^ (r >> 3)) & 7;
        GLOAD16(g + (size_t)r * 64 + ((p ^ key) << 3), ldsb + (i * 64 + wave * 8) * 64);
    }
}

__global__ __launch_bounds__(512, 2) void attn_kernel(const f16* __restrict__ qkv,
                                                      const f16* __restrict__ vT,
                                                      const unsigned long long* __restrict__ bmg,
                                                      f16* __restrict__ ao) {
    __shared__ f16 Ks[256 * 64];
    __shared__ f16 Vs[256 * 64];
    __shared__ unsigned long long BMs[1024];
    const int t = threadIdx.x, wave = t >> 6, lane = t & 63;
    const int l15 = lane & 15, l4 = lane >> 4;
    const int bh = blockIdx.x, bt = bh >> 3, h = bh & 7;
    const int btq = bt * 256, hq = h * 64;
    const f16* qb = qkv + (size_t)btq * 1024 + hq;
    const f16* kb = qb + 512;

    stage_rows512<256>(kb, 1024, 0, Ks, wave, lane);
    stage_v512(vT + (size_t)bh * 16384, Vs, wave, lane);
    GLOAD16((const char*)bmg + (size_t)t * 16, (char*)(BMs + wave * 128));
    __syncthreads();

    for (int s = 0; s < 2; ++s) {
        const int qrow_base = wave * 32 + s * 16;

        f16x8 aq[2];
#pragma unroll
        for (int kk = 0; kk < 2; ++kk)
            aq[kk] = *reinterpret_cast<const f16x8*>(
                qb + (size_t)(qrow_base + l15) * 1024 + kk * 32 + l4 * 8);

        // S^T = K·Q^T : lane holds S[k = ct*16 + l4*4 + r][q = qrow_base + l15]
        f32x4 sc[16];
#pragma unroll
        for (int ct = 0; ct < 16; ++ct) sc[ct] = (f32x4){0.f, 0.f, 0.f, 0.f};
#pragma unroll
        for (int ct = 0; ct < 16; ++ct)
#pragma unroll
            for (int kk = 0; kk < 2; ++kk) {
                int rk = ct * 16 + l15;
                int sk = kk * 4 + l4;
                f16x8 bk_ = *reinterpret_cast<const f16x8*>(Ks + rk * 64 + ((sk ^ (rk & 7)) << 3));
                sc[ct] = __builtin_amdgcn_mfma_f32_16x16x32_f16(bk_, aq[kk], sc[ct], 0, 0, 0);
            }

        // max over raw 64 k-values in-lane + 2 shuffles (shift-invariance: mask later)
        float mx = -1e38f;
#pragma unroll
        for (int ct = 0; ct < 16; ++ct)
#pragma unroll
            for (int r = 0; r < 4; ++r) mx = fmaxf(mx, sc[ct][r]);
        mx = fmaxf(mx, __shfl_xor(mx, 16, 64));
        mx = fmaxf(mx, __shfl_xor(mx, 32, 64));

        const int ig = qrow_base + l15;
        const u16x8* mr = reinterpret_cast<const u16x8*>(BMs + ig * 4);
        u16x8 w0 = mr[0], w1 = mr[1];

        // fused drain + PV: per kkp, consume sc pair -> pack pa -> 4 MFMAs.
        // sched_barrier(0) bounds the scheduler's live window to one iteration.
        f32x4 oacc[4] = {};
        float sum = 0.f;
#pragma unroll
        for (int kkp = 0; kkp < 8; ++kkp) {
            const int ctA = 2 * kkp, ctB = 2 * kkp + 1;
            unsigned mbA = ((kkp < 4) ? (unsigned)w0[ctA] : (unsigned)w1[ctA & 7]) >> (l4 * 4);
            unsigned mbB = ((kkp < 4) ? (unsigned)w0[ctB] : (unsigned)w1[ctB & 7]) >> (l4 * 4);
            float pA0 = __builtin_exp2f(sc[ctA][0] - mx); pA0 = ((mbA >> 0) & 1u) ? pA0 : 0.0f;
            float pA1 = __builtin_exp2f(sc[ctA][1] - mx); pA1 = ((mbA >> 1) & 1u) ? pA1 : 0.0f;
            float pA2 = __builtin_exp2f(sc[ctA][2] - mx); pA2 = ((mbA >> 2) & 1u) ? pA2 : 0.0f;
            float pA3 = __builtin_exp2f(sc[ctA][3] - mx); pA3 = ((mbA >> 3) & 1u) ? pA3 : 0.0f;
            float pB0 = __builtin_exp2f(sc[ctB][0] - mx); pB0 = ((mbB >> 0) & 1u) ? pB0 : 0.0f;
            float pB1 = __builtin_exp2f(sc[ctB][1] - mx); pB1 = ((mbB >> 1) & 1u) ? pB1 : 0.0f;
            float pB2 = __builtin_exp2f(sc[ctB][2] - mx); pB2 = ((mbB >> 2) & 1u) ? pB2 : 0.0f;
            float pB3 = __builtin_exp2f(sc[ctB][3] - mx); pB3 = ((mbB >> 3) & 1u) ? pB3 : 0.0f;
            sum += (pA0 + pA1) + (pA2 + pA3) + (pB0 + pB1) + (pB2 + pB3);
            u32x4 up;
            up[0] = __builtin_bit_cast(unsigned int, __builtin_amdgcn_cvt_pkrtz(pA0, pA1));
            up[1] = __builtin_bit_cast(unsigned int, __builtin_amdgcn_cvt_pkrtz(pA2, pA3));
            up[2] = __builtin_bit_cast(unsigned int, __builtin_amdgcn_cvt_pkrtz(pB0, pB1));
            up[3] = __builtin_bit_cast(unsigned int, __builtin_amdgcn_cvt_pkrtz(pB2, pB3));
            f16x8 pa = __builtin_bit_cast(f16x8, up);
#pragma unroll
            for (int c2 = 0; c2 < 4; ++c2) {
                int d = c2 * 16 + l15;
                int nf0a = kkp * 32 + l4 * 4;
                int nf0b = nf0a + 16;
                int rvA = d * 4 + (nf0a >> 6), rvB = d * 4 + (nf0b >> 6);
                int keyA = (rvA ^ (rvA >> 3)) & 7, keyB = (rvB ^ (rvB >> 3)) & 7;
                u32x2 va = *reinterpret_cast<const u32x2*>(
                    Vs + rvA * 64 + ((((nf0a >> 3) & 7) ^ keyA) << 3) + (nf0a & 7));
                u32x2 vb = *reinterpret_cast<const u32x2*>(
                    Vs + rvB * 64 + ((((nf0b >> 3) & 7) ^ keyB) << 3) + (nf0b & 7));
                u32x4 uv; uv[0] = va[0]; uv[1] = va[1]; uv[2] = vb[0]; uv[3] = vb[1];
                f16x8 bv_ = __builtin_bit_cast(f16x8, uv);
                oacc[c2] = __builtin_amdgcn_mfma_f32_16x16x32_f16(pa, bv_, oacc[c2], 0, 0, 0);
            }
            __builtin_amdgcn_sched_barrier(0);
        }
        sum += __shfl_xor(sum, 16, 64);
        sum += __shfl_xor(sum, 32, 64);
        float rs = 1.0f / sum;
        float rsrow[4];
#pragma unroll
        for (int r = 0; r < 4; ++r) rsrow[r] = __shfl(rs, l4 * 4 + r, 64);

#pragma unroll
        for (int c2 = 0; c2 < 4; ++c2)
#pragma unroll
            for (int r = 0; r < 4; ++r) {
                int nf = qrow_base + l4 * 4 + r;
                int dcol = hq + c2 * 16 + l15;
                ao[((size_t)btq + nf) * 512 + dcol] = (f16)(oacc[c2][r] * rsrow[r]);
            }
    }
}

// ---------------- output projection ----------------

__global__ __launch_bounds__(512) void o_gemm(const f16* __restrict__ A, const f16* __restrict__ W,
                                              const float* __restrict__ bo, float* __restrict__ out) {
    __shared__ __align__(16) f16 lds[32768];     // 64 KB -> 2 blocks/CU
    const int tt = threadIdx.x, wave = tt >> 6, lane = tt & 63;
    const int lb = blockIdx.x, xcd = lb & 7, idx = lb >> 3;
    const int m0 = (xcd * 16 + idx / 2) * 256;
    const int n0 = (idx % 2) * 256;
    f32x4 acc[8][4] = {};
    gemm256_core(A, W, m0, n0, lds, acc, wave, lane);

    const int wr = wave & 1, wc = wave >> 1;
    const int l15 = lane & 15, l4 = lane >> 4;
    float bb[4];
#pragma unroll
    for (int bc = 0; bc < 4; ++bc) bb[bc] = bo[n0 + wc * 64 + bc * 16 + l15];
#pragma unroll
    for (int ar = 0; ar < 8; ++ar)
#pragma unroll
        for (int bc = 0; bc < 4; ++bc) {
            int ng = n0 + wc * 64 + bc * 16 + l15;
#pragma unroll
            for (int r = 0; r < 4; ++r) {
                int mg = m0 + wr * 128 + ar * 16 + l4 * 4 + r;
                out[(size_t)mg * 512 + ng] = acc[ar][bc][r] + bb[bc];
            }
        }
}

// ---------------- launch ----------------

extern "C" void kernel_launch(void* const* d_in, const int* in_sizes, int n_in,
                              void* d_out, int out_size, void* d_ws, size_t ws_size,
                              hipStream_t stream) {
    const float* x   = (const float*)d_in[0];
    const int*   adj = (const int*)d_in[1];
    const float* Wq  = (const float*)d_in[2];
    const float* bq  = (const float*)d_in[3];
    const float* Wk  = (const float*)d_in[4];
    const float* bk  = (const float*)d_in[5];
    const float* Wv  = (const float*)d_in[6];
    const float* bv  = (const float*)d_in[7];
    const float* Wo  = (const float*)d_in[8];
    const float* bo  = (const float*)d_in[9];
    float* out = (float*)d_out;

    char* ws = (char*)d_ws;
    f16*   Wh      = (f16*)ws;                                        // 1572864 B
    f16*   Woh     = (f16*)(ws + 1572864);                            //  524288 B
    float* biasAll = (float*)(ws + 2097152);                          //    6144 B
    unsigned long long* bmask = (unsigned long long*)(ws + 2103296);  //    8192 B
    f16*   xh      = (f16*)(ws + 2111488);                            // [M][512] f16 (reused as ao)
    f16*   qkvb    = (f16*)(ws + 2111488 + (size_t)M_ * 512 * 2);     // [M][1024] f16 (q|k)
    f16*   vTb     = (f16*)(ws + 2111488 + (size_t)M_ * 512 * 2 + (size_t)M_ * 1024 * 2); // [128][8][64][256]
    f16*   aob     = xh;

    prep_all<<<2560, 256, 0, stream>>>(x, xh, Wq, Wk, Wv, Wo, bq, bk, bv, adj,
                                       Wh, Woh, biasAll, bmask);
    qkv_gemm<<<768, 512, 0, stream>>>(xh, Wh, biasAll, qkvb, vTb);
    attn_kernel<<<128 * H_, 512, 0, stream>>>(qkvb, vTb, bmask, aob);
    o_gemm<<<256, 512, 0, stream>>>(aob, Woh, bo, out);
}

// Round 15
// 164.781 us; speedup vs baseline: 1.0699x; 1.0699x over previous
//
#include <hip/hip_runtime.h>

#define NF 256
#define H_ 8
#define M_ 32768

typedef _Float16 f16;
typedef _Float16 f16x8 __attribute__((ext_vector_type(8)));
typedef float f32x4 __attribute__((ext_vector_type(4)));
typedef unsigned short u16x8 __attribute__((ext_vector_type(8)));
typedef unsigned int u32x2 __attribute__((ext_vector_type(2)));
typedef unsigned int u32x4 __attribute__((ext_vector_type(4)));

#define GLOAD16(src, dst) \
  __builtin_amdgcn_global_load_lds((const __attribute__((address_space(1))) void*)(src), \
                                   (__attribute__((address_space(3))) void*)(dst), 16, 0, 0)

#define LDS_FENCE() do { asm volatile("s_waitcnt lgkmcnt(0)" ::: "memory"); \
                         __builtin_amdgcn_sched_barrier(0); } while (0)
#define SBAR() asm volatile("s_barrier" ::: "memory")

// ---------------- 256^2 8-phase GEMM core, BK=64 (R13 proven; R14's BK=32 regressed) ----------------

__device__ __forceinline__ void stageHT(const f16* __restrict__ g, int r0, int k0,
                                        f16* ldst, int wave, int lane) {
    const int key = lane >> 3;
    const int colsw = k0 + (((lane & 7) ^ key) << 3);
#pragma unroll
    for (int i = 0; i < 2; ++i) {
        int r = i * 64 + wave * 8 + key;
        GLOAD16(g + (size_t)(r0 + r) * 512 + colsw, ldst + (i * 64 + wave * 8) * 64);
    }
}

__device__ __forceinline__ void gemm256_core(const f16* __restrict__ A, const f16* __restrict__ W,
                                             int m0, int n0, f16* lds,
                                             f32x4 (&acc)[8][4], int wave, int lane) {
    const int wr = wave & 1, wc = wave >> 1;
    const int l15 = lane & 15, l4 = lane >> 4;
    stageHT(W, n0,        0, lds + 16384, wave, lane);
    stageHT(W, n0 + 128,  0, lds + 24576, wave, lane);
    stageHT(A, m0,        0, lds,         wave, lane);
    stageHT(A, m0 + 128,  0, lds + 8192,  wave, lane);
    stageHT(W, n0,       64, lds + 32768 + 16384, wave, lane);
    stageHT(W, n0 + 128, 64, lds + 32768 + 24576, wave, lane);
    asm volatile("s_waitcnt vmcnt(4)" ::: "memory");
    SBAR();
#pragma unroll
    for (int t = 0; t < 8; ++t) {
        f16* bufA = lds + (t & 1) * 32768;
        f16* bufB = bufA + 16384;
        f16* nA   = lds + ((t & 1) ^ 1) * 32768;
        f16x8 bfr[4][2];
#pragma unroll
        for (int j = 0; j < 4; ++j)
#pragma unroll
            for (int kk = 0; kk < 2; ++kk) {
                int rb = wc * 64 + j * 16 + l15;
                bfr[j][kk] = *reinterpret_cast<const f16x8*>(
                    bufB + rb * 64 + ((((kk << 2) + l4) ^ (rb & 7)) << 3));
            }
#pragma unroll
        for (int q = 0; q < 4; ++q) {
            f16x8 afr[2][2];
#pragma unroll
            for (int rf = 0; rf < 2; ++rf)
#pragma unroll
                for (int kk = 0; kk < 2; ++kk) {
                    int ra = wr * 128 + q * 32 + rf * 16 + l15;
                    afr[rf][kk] = *reinterpret_cast<const f16x8*>(
                        bufA + ra * 64 + ((((kk << 2) + l4) ^ (ra & 7)) << 3));
                }
            if (q == 0 && t < 7) stageHT(A, m0,       (t + 1) * 64, nA,          wave, lane);
            if (q == 1 && t < 7) stageHT(A, m0 + 128, (t + 1) * 64, nA + 8192,   wave, lane);
            if (q == 2 && t < 6) stageHT(W, n0,       (t + 2) * 64, bufB,        wave, lane);
            if (q == 3 && t < 6) stageHT(W, n0 + 128, (t + 2) * 64, bufB + 8192, wave, lane);
            SBAR();
            LDS_FENCE();
            __builtin_amdgcn_s_setprio(1);
#pragma unroll
            for (int rf = 0; rf < 2; ++rf)
#pragma unroll
                for (int j = 0; j < 4; ++j)
#pragma unroll
                    for (int kk = 0; kk < 2; ++kk)
                        acc[q * 2 + rf][j] = __builtin_amdgcn_mfma_f32_16x16x32_f16(
                            afr[rf][kk], bfr[j][kk], acc[q * 2 + rf][j], 0, 0, 0);
            __builtin_amdgcn_s_setprio(0);
            if (q < 3) SBAR();
        }
        if (t < 6) { asm volatile("s_waitcnt vmcnt(4)" ::: "memory"); }
        else       { asm volatile("s_waitcnt vmcnt(0)" ::: "memory"); }
        SBAR();
    }
}

// ---------------- conversion / prep ----------------

#define QSCALE 0.1803368801111204f   // (1/8) * log2(e)

__global__ void prep_all(const float* __restrict__ x, f16* __restrict__ xh,
                         const float* __restrict__ Wq, const float* __restrict__ Wk,
                         const float* __restrict__ Wv, const float* __restrict__ Wo,
                         const float* __restrict__ bq, const float* __restrict__ bk,
                         const float* __restrict__ bv, const int* __restrict__ adj,
                         f16* __restrict__ Wh, f16* __restrict__ Woh,
                         float* __restrict__ biasAll, unsigned long long* __restrict__ bmask) {
    if (blockIdx.x < 2048) {
        int idx = blockIdx.x * 256 + threadIdx.x;
        for (; idx < M_ * 512 / 8; idx += 2048 * 256) {
            const float4* s = reinterpret_cast<const float4*>(x + (size_t)idx * 8);
            float4 v0 = s[0], v1 = s[1];
            f16x8 o;
            o[0] = (f16)v0.x; o[1] = (f16)v0.y; o[2] = (f16)v0.z; o[3] = (f16)v0.w;
            o[4] = (f16)v1.x; o[5] = (f16)v1.y; o[6] = (f16)v1.z; o[7] = (f16)v1.w;
            *reinterpret_cast<f16x8*>(xh + (size_t)idx * 8) = o;
        }
        return;
    }
    const int tid = (blockIdx.x - 2048) * 256 + threadIdx.x;
    {
        const float* s; f16* d; float sc = 1.0f;
        int pp = tid >> 15, off = tid & 32767;
        if (pp == 0)      { s = Wq; d = Wh;              sc = QSCALE; }
        else if (pp == 1) { s = Wk; d = Wh + 512 * 512; }
        else if (pp == 2) { s = Wv; d = Wh + 2 * 512 * 512; }
        else              { s = Wo; d = Woh; }
        const float4* sv4 = reinterpret_cast<const float4*>(s + (size_t)off * 8);
        float4 v0 = sv4[0], v1 = sv4[1];
        f16x8 o;
        o[0] = (f16)(v0.x * sc); o[1] = (f16)(v0.y * sc);
        o[2] = (f16)(v0.z * sc); o[3] = (f16)(v0.w * sc);
        o[4] = (f16)(v1.x * sc); o[5] = (f16)(v1.y * sc);
        o[6] = (f16)(v1.z * sc); o[7] = (f16)(v1.w * sc);
        *reinterpret_cast<f16x8*>(d + (size_t)off * 8) = o;
    }
    if (tid < 1536) {
        float v = (tid < 512) ? QSCALE * bq[tid] : (tid < 1024) ? bk[tid - 512] : bv[tid - 1024];
        biasAll[tid] = v;
    }
    if (tid < 65536) {
        unsigned long long bal = __ballot(adj[tid] > 0);
        if ((tid & 63) == 0) bmask[tid >> 6] = bal;
    }
}

// ---------------- fused QKV GEMM (R13 proven epilogues) ----------------

__global__ __launch_bounds__(512) void qkv_gemm(const f16* __restrict__ A, const f16* __restrict__ W,
                                                const float* __restrict__ biasAll,
                                                f16* __restrict__ out, f16* __restrict__ vT) {
    __shared__ __align__(16) f16 lds[65536];
    const int tt = threadIdx.x, wave = tt >> 6, lane = tt & 63;
    const int lb = blockIdx.x, xcd = lb & 7, idx = lb >> 3;
    const int m0 = (xcd * 16 + idx / 6) * 256;
    const int n0 = (idx % 6) * 256;
    f32x4 acc[8][4] = {};
    gemm256_core(A, W, m0, n0, lds, acc, wave, lane);

    const int wr = wave & 1, wc = wave >> 1;
    const int l15 = lane & 15, l4 = lane >> 4;
    f16* epi = lds;
    const bool isV = (n0 >= 1024);
    float bb[4];
#pragma unroll
    for (int bc = 0; bc < 4; ++bc) bb[bc] = biasAll[n0 + wc * 64 + bc * 16 + l15];
#pragma unroll
    for (int half = 0; half < 2; ++half) {
        if (wr == half) {
            if (!isV) {
#pragma unroll
                for (int ar = 0; ar < 8; ++ar)
#pragma unroll
                    for (int bc = 0; bc < 4; ++bc)
#pragma unroll
                        for (int r = 0; r < 4; ++r)
                            epi[(ar * 16 + l4 * 4 + r) * 264 + wc * 64 + bc * 16 + l15] =
                                (f16)(acc[ar][bc][r] + bb[bc]);
            } else {
                // transposed: epiT[dk_local][nf_in_half], stride 136 (272 B, b128-aligned)
#pragma unroll
                for (int ar = 0; ar < 8; ++ar)
#pragma unroll
                    for (int bc = 0; bc < 4; ++bc)
#pragma unroll
                        for (int r = 0; r < 4; ++r)
                            epi[(wc * 64 + bc * 16 + l15) * 136 + ar * 16 + l4 * 4 + r] =
                                (f16)(acc[ar][bc][r] + bb[bc]);
            }
        }
        LDS_FENCE();
        SBAR();
        if (!isV) {
            const int rr = tt >> 5, slot = tt & 31;
#pragma unroll
            for (int p = 0; p < 8; ++p) {
                int row = p * 16 + rr;
                *reinterpret_cast<f16x8*>(out + (size_t)(m0 + half * 128 + row) * 1024 + n0 + slot * 8) =
                    *reinterpret_cast<const f16x8*>(epi + row * 264 + slot * 8);
            }
        } else {
            f16* vdst = vT + (size_t)(m0 >> 8) * 8 * 64 * 256 + (size_t)(n0 - 1024) * 256;
            const int dk = tt >> 1;
#pragma unroll
            for (int i = 0; i < 8; ++i) {
                int nf0 = (tt & 1) * 64 + i * 8;
                *reinterpret_cast<f16x8*>(vdst + (size_t)dk * 256 + half * 128 + nf0) =
                    *reinterpret_cast<const f16x8*>(epi + dk * 136 + nf0);
            }
        }
        SBAR();
    }
}

// ---------------- attention (R12 structure + XCD head-clustering + T5 setprio) ----------------
// Block mapping: xcd = lb&7; bt = xcd*16 + (idx>>3); h = idx&7 — the 8 heads of one
// bt run co-temporally on ONE XCD, so its qkvb rows (shared 2KB lines across heads)
// and vT panel are fetched into that XCD's L2 once instead of 8 times (T1).

template <int NR>
__device__ __forceinline__ void stage_rows512(const f16* __restrict__ g, int ld, int coff,
                                              f16* ldsb, int wave, int lane) {
    const int rr = wave * 8 + (lane >> 3);
    const int p  = lane & 7;
#pragma unroll
    for (int i = 0; i < NR / 64; ++i) {
        int r = i * 64 + rr;
        int col = ((p ^ (r & 7)) << 3);
        GLOAD16(g + (size_t)r * ld + coff + col, ldsb + (i * 64 + wave * 8) * 64);
    }
}

__device__ __forceinline__ void stage_v512(const f16* __restrict__ g, f16* ldsb,
                                           int wave, int lane) {
    const int rr = wave * 8 + (lane >> 3);
    const int p  = lane & 7;
#pragma unroll
    for (int i = 0; i < 4; ++i) {
        int r = i * 64 + rr;
        int key = (r ^ (r >> 3)) & 7;
        GLOAD16(g + (size_t)r * 64 + ((p ^ key) << 3), ldsb + (i * 64 + wave * 8) * 64);
    }
}

__global__ __launch_bounds__(512, 2) void attn_kernel(const f16* __restrict__ qkv,
                                                      const f16* __restrict__ vT,
                                                      const unsigned long long* __restrict__ bmg,
                                                      f16* __restrict__ ao) {
    __shared__ f16 Ks[256 * 64];
    __shared__ f16 Vs[256 * 64];
    __shared__ unsigned long long BMs[1024];
    const int t = threadIdx.x, wave = t >> 6, lane = t & 63;
    const int l15 = lane & 15, l4 = lane >> 4;
    const int lb = blockIdx.x, xcd = lb & 7, idx = lb >> 3;   // 128 blocks per XCD
    const int bt = xcd * 16 + (idx >> 3), h = idx & 7;
    const int bh = bt * 8 + h;
    const int btq = bt * 256, hq = h * 64;
    const f16* qb = qkv + (size_t)btq * 1024 + hq;
    const f16* kb = qb + 512;

    stage_rows512<256>(kb, 1024, 0, Ks, wave, lane);
    stage_v512(vT + (size_t)bh * 16384, Vs, wave, lane);
    GLOAD16((const char*)bmg + (size_t)t * 16, (char*)(BMs + wave * 128));
    __syncthreads();

    for (int s = 0; s < 2; ++s) {
        const int qrow_base = wave * 32 + s * 16;

        f16x8 aq[2];
#pragma unroll
        for (int kk = 0; kk < 2; ++kk)
            aq[kk] = *reinterpret_cast<const f16x8*>(
                qb + (size_t)(qrow_base + l15) * 1024 + kk * 32 + l4 * 8);

        // S^T = K·Q^T : lane holds S[k = ct*16 + l4*4 + r][q = qrow_base + l15]
        f32x4 sc[16];
#pragma unroll
        for (int ct = 0; ct < 16; ++ct) sc[ct] = (f32x4){0.f, 0.f, 0.f, 0.f};
        __builtin_amdgcn_s_setprio(1);
#pragma unroll
        for (int ct = 0; ct < 16; ++ct)
#pragma unroll
            for (int kk = 0; kk < 2; ++kk) {
                int rk = ct * 16 + l15;
                int sk = kk * 4 + l4;
                f16x8 bk_ = *reinterpret_cast<const f16x8*>(Ks + rk * 64 + ((sk ^ (rk & 7)) << 3));
                sc[ct] = __builtin_amdgcn_mfma_f32_16x16x32_f16(bk_, aq[kk], sc[ct], 0, 0, 0);
            }
        __builtin_amdgcn_s_setprio(0);

        // max over raw 64 k-values in-lane + 2 shuffles (shift-invariance: mask later)
        float mx = -1e38f;
#pragma unroll
        for (int ct = 0; ct < 16; ++ct)
#pragma unroll
            for (int r = 0; r < 4; ++r) mx = fmaxf(mx, sc[ct][r]);
        mx = fmaxf(mx, __shfl_xor(mx, 16, 64));
        mx = fmaxf(mx, __shfl_xor(mx, 32, 64));

        const int ig = qrow_base + l15;
        const u16x8* mr = reinterpret_cast<const u16x8*>(BMs + ig * 4);
        u16x8 w0 = mr[0], w1 = mr[1];

        // fused drain + PV: per kkp, consume sc pair -> pack pa -> 4 MFMAs.
        // sched_barrier(0) bounds the scheduler's live window to one iteration
        // (R12 fix: prevents hoisting all ds_reads/packs co-live -> no spill).
        f32x4 oacc[4] = {};
        float sum = 0.f;
#pragma unroll
        for (int kkp = 0; kkp < 8; ++kkp) {
            const int ctA = 2 * kkp, ctB = 2 * kkp + 1;
            unsigned mbA = ((kkp < 4) ? (unsigned)w0[ctA] : (unsigned)w1[ctA & 7]) >> (l4 * 4);
            unsigned mbB = ((kkp < 4) ? (unsigned)w0[ctB] : (unsigned)w1[ctB & 7]) >> (l4 * 4);
            float pA0 = __builtin_exp2f(sc[ctA][0] - mx); pA0 = ((mbA >> 0) & 1u) ? pA0 : 0.0f;
            float pA1 = __builtin_exp2f(sc[ctA][1] - mx); pA1 = ((mbA >> 1) & 1u) ? pA1 : 0.0f;
            float pA2 = __builtin_exp2f(sc[ctA][2] - mx); pA2 = ((mbA >> 2) & 1u) ? pA2 : 0.0f;
            float pA3 = __builtin_exp2f(sc[ctA][3] - mx); pA3 = ((mbA >> 3) & 1u) ? pA3 : 0.0f;
            float pB0 = __builtin_exp2f(sc[ctB][0] - mx); pB0 = ((mbB >> 0) & 1u) ? pB0 : 0.0f;
            float pB1 = __builtin_exp2f(sc[ctB][1] - mx); pB1 = ((mbB >> 1) & 1u) ? pB1 : 0.0f;
            float pB2 = __builtin_exp2f(sc[ctB][2] - mx); pB2 = ((mbB >> 2) & 1u) ? pB2 : 0.0f;
            float pB3 = __builtin_exp2f(sc[ctB][3] - mx); pB3 = ((mbB >> 3) & 1u) ? pB3 : 0.0f;
            sum += (pA0 + pA1) + (pA2 + pA3) + (pB0 + pB1) + (pB2 + pB3);
            u32x4 up;
            up[0] = __builtin_bit_cast(unsigned int, __builtin_amdgcn_cvt_pkrtz(pA0, pA1));
            up[1] = __builtin_bit_cast(unsigned int, __builtin_amdgcn_cvt_pkrtz(pA2, pA3));
            up[2] = __builtin_bit_cast(unsigned int, __builtin_amdgcn_cvt_pkrtz(pB0, pB1));
            up[3] = __builtin_bit_cast(unsigned int, __builtin_amdgcn_cvt_pkrtz(pB2, pB3));
            f16x8 pa = __builtin_bit_cast(f16x8, up);
            __builtin_amdgcn_s_setprio(1);
#pragma unroll
            for (int c2 = 0; c2 < 4; ++c2) {
                int d = c2 * 16 + l15;
                int nf0a = kkp * 32 + l4 * 4;
                int nf0b = nf0a + 16;
                int rvA = d * 4 + (nf0a >> 6), rvB = d * 4 + (nf0b >> 6);
                int keyA = (rvA ^ (rvA >> 3)) & 7, keyB = (rvB ^ (rvB >> 3)) & 7;
                u32x2 va = *reinterpret_cast<const u32x2*>(
                    Vs + rvA * 64 + ((((nf0a >> 3) & 7) ^ keyA) << 3) + (nf0a & 7));
                u32x2 vb = *reinterpret_cast<const u32x2*>(
                    Vs + rvB * 64 + ((((nf0b >> 3) & 7) ^ keyB) << 3) + (nf0b & 7));
                u32x4 uv; uv[0] = va[0]; uv[1] = va[1]; uv[2] = vb[0]; uv[3] = vb[1];
                f16x8 bv_ = __builtin_bit_cast(f16x8, uv);
                oacc[c2] = __builtin_amdgcn_mfma_f32_16x16x32_f16(pa, bv_, oacc[c2], 0, 0, 0);
            }
            __builtin_amdgcn_s_setprio(0);
            __builtin_amdgcn_sched_barrier(0);
        }
        sum += __shfl_xor(sum, 16, 64);
        sum += __shfl_xor(sum, 32, 64);
        float rs = 1.0f / sum;
        float rsrow[4];
#pragma unroll
        for (int r = 0; r < 4; ++r) rsrow[r] = __shfl(rs, l4 * 4 + r, 64);

#pragma unroll
        for (int c2 = 0; c2 < 4; ++c2)
#pragma unroll
            for (int r = 0; r < 4; ++r) {
                int nf = qrow_base + l4 * 4 + r;
                int dcol = hq + c2 * 16 + l15;
                ao[((size_t)btq + nf) * 512 + dcol] = (f16)(oacc[c2][r] * rsrow[r]);
            }
    }
}

// ---------------- output projection (R13) ----------------

__global__ __launch_bounds__(512) void o_gemm(const f16* __restrict__ A, const f16* __restrict__ W,
                                              const float* __restrict__ bo, float* __restrict__ out) {
    __shared__ __align__(16) f16 lds[65536];
    const int tt = threadIdx.x, wave = tt >> 6, lane = tt & 63;
    const int lb = blockIdx.x, xcd = lb & 7, idx = lb >> 3;
    const int m0 = (xcd * 16 + idx / 2) * 256;
    const int n0 = (idx % 2) * 256;
    f32x4 acc[8][4] = {};
    gemm256_core(A, W, m0, n0, lds, acc, wave, lane);

    const int wr = wave & 1, wc = wave >> 1;
    const int l15 = lane & 15, l4 = lane >> 4;
    float bb[4];
#pragma unroll
    for (int bc = 0; bc < 4; ++bc) bb[bc] = bo[n0 + wc * 64 + bc * 16 + l15];
#pragma unroll
    for (int ar = 0; ar < 8; ++ar)
#pragma unroll
        for (int bc = 0; bc < 4; ++bc) {
            int ng = n0 + wc * 64 + bc * 16 + l15;
#pragma unroll
            for (int r = 0; r < 4; ++r) {
                int mg = m0 + wr * 128 + ar * 16 + l4 * 4 + r;
                out[(size_t)mg * 512 + ng] = acc[ar][bc][r] + bb[bc];
            }
        }
}

// ---------------- launch ----------------

extern "C" void kernel_launch(void* const* d_in, const int* in_sizes, int n_in,
                              void* d_out, int out_size, void* d_ws, size_t ws_size,
                              hipStream_t stream) {
    const float* x   = (const float*)d_in[0];
    const int*   adj = (const int*)d_in[1];
    const float* Wq  = (const float*)d_in[2];
    const float* bq  = (const float*)d_in[3];
    const float* Wk  = (const float*)d_in[4];
    const float* bk  = (const float*)d_in[5];
    const float* Wv  = (const float*)d_in[6];
    const float* bv  = (const float*)d_in[7];
    const float* Wo  = (const float*)d_in[8];
    const float* bo  = (const float*)d_in[9];
    float* out = (float*)d_out;

    char* ws = (char*)d_ws;
    f16*   Wh      = (f16*)ws;                                        // 1572864 B
    f16*   Woh     = (f16*)(ws + 1572864);                            //  524288 B
    float* biasAll = (float*)(ws + 2097152);                          //    6144 B
    unsigned long long* bmask = (unsigned long long*)(ws + 2103296);  //    8192 B
    f16*   xh      = (f16*)(ws + 2111488);                            // [M][512] f16 (reused as ao)
    f16*   qkvb    = (f16*)(ws + 2111488 + (size_t)M_ * 512 * 2);     // [M][1024] f16 (q|k)
    f16*   vTb     = (f16*)(ws + 2111488 + (size_t)M_ * 512 * 2 + (size_t)M_ * 1024 * 2); // [128][8][64][256]
    f16*   aob     = xh;

    prep_all<<<2560, 256, 0, stream>>>(x, xh, Wq, Wk, Wv, Wo, bq, bk, bv, adj,
                                       Wh, Woh, biasAll, bmask);
    qkv_gemm<<<768, 512, 0, stream>>>(xh, Wh, biasAll, qkvb, vTb);
    attn_kernel<<<128 * H_, 512, 0, stream>>>(qkvb, vTb, bmask, aob);
    o_gemm<<<256, 512, 0, stream>>>(aob, Woh, bo, out);
}